// Round 3
// baseline (123.530 us; speedup 1.0000x reference)
//
#include <hip/hip_runtime.h>
#include <hip/hip_bf16.h>

#define B_    2
#define H_    16
#define HKV_  4
#define SQ_   1024
#define SP_   1024
#define SK_   2048
#define D_    128
#define QBLK  64
#define KVBLK 64

typedef __attribute__((ext_vector_type(8))) __bf16 bf16x8;
typedef __attribute__((ext_vector_type(4))) __bf16 bf16x4;
typedef __attribute__((ext_vector_type(4))) float  f32x4;

__device__ inline __bf16 f2bf(float f) { return (__bf16)f; }

__global__ __launch_bounds__(256, 2)
void attn_fused_kernel(const float* __restrict__ Q, const float* __restrict__ Kin,
                       const float* __restrict__ Vin, const float* __restrict__ PK,
                       const float* __restrict__ PV, float* __restrict__ Out,
                       float* __restrict__ opk, float* __restrict__ opv)
{
    // double-buffered K/V + per-wave P; all linear + XOR swizzle (byte ^= (row&7)<<4)
    __shared__ __align__(16) __bf16 Klds[2][KVBLK * D_];   // 2 x 16 KB
    __shared__ __align__(16) __bf16 Vlds[2][D_ * KVBLK];   // 2 x 16 KB  (transposed [d][k])
    __shared__ __align__(16) __bf16 Plds[4 * 16 * KVBLK];  // 8 KB

    const int tid = threadIdx.x;
    const int qtx = blockIdx.x;
    const int h   = blockIdx.y;
    const int b   = blockIdx.z;

    if (qtx == 16) {
        // ---- fused present_key/present_value copy (32 blocks) ----
        const int n4 = B_*HKV_*SK_*(D_/4);        // 524288 float4 per output
        const int sid = b*16 + h;                 // 0..31
        #pragma unroll 4
        for (int i = 0; i < 128; ++i) {
            int idx = sid*32768 + i*256 + tid;    // 0 .. 2*n4-1
            bool isV = idx >= n4;
            int id2 = isV ? idx - n4 : idx;
            int d4 = id2 & 31;
            int s  = (id2 >> 5) & (SK_-1);
            int bg = id2 >> 16;
            int bb = bg >> 2, g = bg & 3;
            const float* srcp = (s < SP_)
                ? (isV ? PV : PK) + (((size_t)bg)*SP_ + s)*(size_t)D_ + d4*4
                : (isV ? Vin : Kin) + (((size_t)(bb*H_ + 4*g))*SQ_ + (s - SP_))*(size_t)D_ + d4*4;
            float4 v = *(const float4*)srcp;
            *(float4*)((isV ? opv : opk) + (size_t)id2*4) = v;
        }
        return;
    }

    const int qt = b ? (15 - qtx) : qtx;          // balance: paired blocks sum to const work
    const int lane = tid & 63;
    const int w    = tid >> 6;
    const int lr   = lane & 15;
    const int lg   = lane >> 4;
    const int q0w  = qt * QBLK + w * 16;

    const float scale_l2e = 0.08838834764831845f * 1.4426950408889634f; // 1/sqrt(128)*log2e

    // ---- Q fragments, pre-scaled (scores land in log2 domain); q-row = lr ----
    bf16x8 qf[4];
    {
        const float* qsrc = Q + (((size_t)b*H_ + h)*SQ_ + q0w + lr)*(size_t)D_ + lg*8;
        #pragma unroll
        for (int c = 0; c < 4; ++c) {
            f32x4 a0 = *(const f32x4*)(qsrc + c*32);
            f32x4 a1 = *(const f32x4*)(qsrc + c*32 + 4);
            bf16x8 f;
            #pragma unroll
            for (int j = 0; j < 4; ++j) {
                f[j]   = f2bf(a0[j] * scale_l2e);
                f[j+4] = f2bf(a1[j] * scale_l2e);
            }
            qf[c] = f;
        }
    }

    f32x4 o[8];   // o[dt][r] = O[q = q0w+lr][d = dt*16 + lg*4 + r]
    #pragma unroll
    for (int i = 0; i < 8; ++i) o[i] = (f32x4){0.f,0.f,0.f,0.f};
    float m_r = -1e30f, l_r = 0.f;

    const int nt = qt + 17;
    const size_t pk_base = (((size_t)b*HKV_ + (h>>2))*SP_)*(size_t)D_;
    const size_t kn_base = (((size_t)b*H_   + h     )*SQ_)*(size_t)D_;

    f32x4 kreg[4][2], vreg[2][4];

    auto loadKV = [&](const float* ks, const float* vs) {
        #pragma unroll
        for (int i = 0; i < 4; ++i) {
            int idx = i*256 + tid, row = idx >> 4, c8 = idx & 15;
            kreg[i][0] = *(const f32x4*)(ks + row*D_ + c8*8);
            kreg[i][1] = *(const f32x4*)(ks + row*D_ + c8*8 + 4);
        }
        #pragma unroll
        for (int i = 0; i < 2; ++i) {
            int blk = i*256 + tid, bk = blk & 15, bd = blk >> 4;
            #pragma unroll
            for (int kk = 0; kk < 4; ++kk)
                vreg[i][kk] = *(const f32x4*)(vs + (4*bk+kk)*D_ + bd*4);
        }
    };
    auto writeKV = [&](int buf) {
        #pragma unroll
        for (int i = 0; i < 4; ++i) {
            int idx = i*256 + tid, row = idx >> 4, c8 = idx & 15;
            bf16x8 f;
            #pragma unroll
            for (int j = 0; j < 4; ++j) {
                f[j]   = f2bf(kreg[i][0][j]);
                f[j+4] = f2bf(kreg[i][1][j]);
            }
            int off = (row*256 + c8*16) ^ ((row & 7) << 4);
            *(bf16x8*)((char*)Klds[buf] + off) = f;
        }
        #pragma unroll
        for (int i = 0; i < 2; ++i) {
            int blk = i*256 + tid, bk = blk & 15, bd = blk >> 4;
            #pragma unroll
            for (int j = 0; j < 4; ++j) {
                int d = 4*bd + j;
                bf16x4 t;
                t[0]=f2bf(vreg[i][0][j]); t[1]=f2bf(vreg[i][1][j]);
                t[2]=f2bf(vreg[i][2][j]); t[3]=f2bf(vreg[i][3][j]);
                int off = (d*128 + bk*8) ^ ((d & 7) << 4);
                *(bf16x4*)((char*)Vlds[buf] + off) = t;
            }
        }
    };

    // ---- prologue: tile 0 (always past) -> regs -> buf0 ----
    loadKV(PK + pk_base, PV + pk_base);
    writeKV(0);
    __syncthreads();

    for (int kt = 0; kt < nt; ++kt) {
        const int cur = kt & 1;

        // ---- issue prefetch of tile kt+1 (consumed at end of this region) ----
        if (kt + 1 < nt) {
            const int k1 = (kt + 1) * KVBLK;
            const float* ks = (k1 < SP_) ? PK + pk_base + (size_t)k1*D_
                                         : Kin + kn_base + (size_t)(k1 - SP_)*D_;
            const float* vs = (k1 < SP_) ? PV + pk_base + (size_t)k1*D_
                                         : Vin + kn_base + (size_t)(k1 - SP_)*D_;
            loadKV(ks, vs);
        }

        const char* Kb = (const char*)Klds[cur];
        const char* Vb = (const char*)Vlds[cur];

        // ---- QK^T swapped: lane holds k = n*16+lg*4+r, q = lr ----
        f32x4 s[4];
        #pragma unroll
        for (int n = 0; n < 4; ++n) s[n] = (f32x4){0.f,0.f,0.f,0.f};
        __builtin_amdgcn_s_setprio(1);
        #pragma unroll
        for (int n = 0; n < 4; ++n) {
            #pragma unroll
            for (int c = 0; c < 4; ++c) {
                int off = ((n*16 + lr)*256 + c*64 + lg*16) ^ ((lr & 7) << 4);
                bf16x8 kf = *(const bf16x8*)(Kb + off);
                s[n] = __builtin_amdgcn_mfma_f32_16x16x32_bf16(kf, qf[c], s[n], 0, 0, 0);
            }
        }
        __builtin_amdgcn_s_setprio(0);

        // ---- causal mask: provably only the last tile ----
        float p[16];
        if (kt == nt - 1) {
            const int qv = q0w + lr + SP_;
            const int k0 = kt * KVBLK;
            #pragma unroll
            for (int n = 0; n < 4; ++n)
                #pragma unroll
                for (int r = 0; r < 4; ++r) {
                    int kg = k0 + n*16 + lg*4 + r;
                    p[n*4+r] = (kg <= qv) ? s[n][r] : -1e30f;
                }
        } else {
            #pragma unroll
            for (int n = 0; n < 4; ++n)
                #pragma unroll
                for (int r = 0; r < 4; ++r) p[n*4+r] = s[n][r];
        }

        // ---- online softmax with defer-max (T13, THR=8 in log2 domain) ----
        float mx = p[0];
        #pragma unroll
        for (int i = 1; i < 16; ++i) mx = fmaxf(mx, p[i]);
        mx = fmaxf(mx, __shfl_xor(mx, 16));
        mx = fmaxf(mx, __shfl_xor(mx, 32));
        if (!__all(mx <= m_r + 8.0f)) {
            float mnew  = fmaxf(m_r, mx);
            float alpha = exp2f(m_r - mnew);
            m_r = mnew;
            l_r *= alpha;
            #pragma unroll
            for (int dt = 0; dt < 8; ++dt) {
                o[dt][0] *= alpha; o[dt][1] *= alpha;
                o[dt][2] *= alpha; o[dt][3] *= alpha;
            }
        }
        float psum = 0.f;
        #pragma unroll
        for (int i = 0; i < 16; ++i) { p[i] = exp2f(p[i] - m_r); psum += p[i]; }
        psum += __shfl_xor(psum, 16);
        psum += __shfl_xor(psum, 32);
        l_r += psum;

        // ---- P -> per-wave LDS (swizzled) ----
        char* Pw = (char*)Plds + w*2048;
        #pragma unroll
        for (int n = 0; n < 4; ++n) {
            bf16x4 t;
            t[0]=f2bf(p[n*4+0]); t[1]=f2bf(p[n*4+1]);
            t[2]=f2bf(p[n*4+2]); t[3]=f2bf(p[n*4+3]);
            int off = (lr*128 + n*32 + lg*8) ^ ((lr & 7) << 4);
            *(bf16x4*)(Pw + off) = t;
        }

        // ---- PV swapped: O^T[d][q] += mfma(V, P) ----
        __builtin_amdgcn_s_setprio(1);
        #pragma unroll
        for (int kk = 0; kk < 2; ++kk) {
            int poff = (lr*128 + kk*64 + lg*16) ^ ((lr & 7) << 4);
            bf16x8 pa = *(const bf16x8*)(Pw + poff);
            #pragma unroll
            for (int dt = 0; dt < 8; ++dt) {
                int voff = ((dt*16 + lr)*128 + kk*64 + lg*16) ^ ((lr & 7) << 4);
                bf16x8 vf = *(const bf16x8*)(Vb + voff);
                o[dt] = __builtin_amdgcn_mfma_f32_16x16x32_bf16(vf, pa, o[dt], 0, 0, 0);
            }
        }
        __builtin_amdgcn_s_setprio(0);

        // ---- staged regs (tile kt+1) -> other buffer; single barrier per tile ----
        if (kt + 1 < nt) {
            writeKV(cur ^ 1);
            __syncthreads();
        }
    }

    // ---- epilogue: lane owns q-row q0w+lr ----
    float inv = 1.0f / l_r;
    float* orow = Out + (((size_t)b*H_ + h)*SQ_ + q0w + lr)*(size_t)D_;
    #pragma unroll
    for (int dt = 0; dt < 8; ++dt) {
        f32x4 st;
        st[0]=o[dt][0]*inv; st[1]=o[dt][1]*inv;
        st[2]=o[dt][2]*inv; st[3]=o[dt][3]*inv;
        *(f32x4*)(orow + dt*16 + lg*4) = st;
    }
}

extern "C" void kernel_launch(void* const* d_in, const int* in_sizes, int n_in,
                              void* d_out, int out_size, void* d_ws, size_t ws_size,
                              hipStream_t stream) {
    const float* Q   = (const float*)d_in[0];
    const float* K   = (const float*)d_in[1];
    const float* V   = (const float*)d_in[2];
    const float* PK  = (const float*)d_in[3];
    const float* PV  = (const float*)d_in[4];
    float* out = (float*)d_out;
    float* opk = out + (size_t)B_*H_*SQ_*D_;
    float* opv = opk + (size_t)B_*HKV_*SK_*D_;

    dim3 agrid(17, H_, B_);   // x==16 -> copy blocks
    attn_fused_kernel<<<agrid, 256, 0, stream>>>(Q, K, V, PK, PV, out, opk, opv);
}

// Round 4
// 81.211 us; speedup vs baseline: 1.5211x; 1.5211x over previous
//
#include <hip/hip_runtime.h>
#include <hip/hip_bf16.h>

#define B_    2
#define H_    16
#define HKV_  4
#define SQ_   1024
#define SP_   1024
#define SK_   2048
#define D_    128
#define QBLK  64
#define KVBLK 64

typedef __attribute__((ext_vector_type(8))) __bf16 bf16x8;
typedef __attribute__((ext_vector_type(4))) __bf16 bf16x4;
typedef __attribute__((ext_vector_type(4))) float  f32x4;

__device__ inline __bf16 f2bf(float f) { return (__bf16)f; }

__global__ __launch_bounds__(256, 2)
void attn_fused_kernel(const float* __restrict__ Q, const float* __restrict__ Kin,
                       const float* __restrict__ Vin, const float* __restrict__ PK,
                       const float* __restrict__ PV, float* __restrict__ Out,
                       float* __restrict__ opk, float* __restrict__ opv)
{
    // Linear layouts + XOR swizzle (byte ^= (row&7)<<4) on write AND read.
    __shared__ __align__(16) __bf16 Klds[KVBLK * D_];     // [64 k][128 d], 16 KB
    __shared__ __align__(16) __bf16 Vlds[D_ * KVBLK];     // [128 d][64 k], 16 KB
    __shared__ __align__(16) __bf16 Plds[4 * 16 * KVBLK]; // per-wave [16 q][64 k], 8 KB

    const int tid = threadIdx.x;
    const int id  = blockIdx.x;

    if (id >= 512) {
        // ---- fused present_key/present_value copy, XCD-aligned ----
        // cid: bgc = cid&7 (matches id%8 XCD residency of group bgc's attn blocks)
        const int cid = id - 512;              // 0..63
        const int bgc = cid & 7;               // b*4+g
        const int sub = cid >> 3;              // 0..7
        const int isV = sub >> 2;
        const int q4  = sub & 3;
        const int bb = bgc >> 2, g = bgc & 3;
        const float* past = isV ? PV : PK;
        const float* cur  = isV ? Vin : Kin;
        float* dst = isV ? opv : opk;
        const int base = bgc*65536 + q4*16384;
        #pragma unroll 4
        for (int i = 0; i < 64; ++i) {
            int id2 = base + i*256 + tid;
            int d4 = id2 & 31;
            int s  = (id2 >> 5) & (SK_-1);
            const float* srcp = (s < SP_)
                ? past + (((size_t)bgc)*SP_ + s)*(size_t)D_ + d4*4
                : cur  + (((size_t)(bb*H_ + 4*g))*SQ_ + (s - SP_))*(size_t)D_ + d4*4;
            float4 v = *(const float4*)srcp;
            *(float4*)(dst + (size_t)id2*4) = v;
        }
        return;
    }

    // ---- XCD-group swizzle: id%8 == kv_group (b*4 + h>>2) ----
    const int grp = id & 7;         // b*4 + (h>>2)
    const int rest = id >> 3;
    const int hi  = rest & 3;       // h & 3
    const int qt  = rest >> 2;      // 0..15
    const int b   = grp >> 2;
    const int h   = (grp & 3)*4 + hi;

    const int lane = tid & 63;
    const int w    = tid >> 6;
    const int lr   = lane & 15;
    const int lg   = lane >> 4;
    const int q0w  = qt * QBLK + w * 16;

    const float scale_l2e = 0.08838834764831845f * 1.4426950408889634f; // 1/sqrt(128)*log2e

    // ---- Q fragments, pre-scaled (scores land in log2 domain); q-row = lr ----
    bf16x8 qf[4];
    {
        const float* qsrc = Q + (((size_t)b*H_ + h)*SQ_ + q0w + lr)*(size_t)D_ + lg*8;
        #pragma unroll
        for (int c = 0; c < 4; ++c) {
            f32x4 a0 = *(const f32x4*)(qsrc + c*32);
            f32x4 a1 = *(const f32x4*)(qsrc + c*32 + 4);
            bf16x8 f;
            #pragma unroll
            for (int j = 0; j < 4; ++j) {
                f[j]   = f2bf(a0[j] * scale_l2e);
                f[j+4] = f2bf(a1[j] * scale_l2e);
            }
            qf[c] = f;
        }
    }

    f32x4 o[8];   // o[dt][r] = O[q = q0w+lr][d = dt*16 + lg*4 + r]
    #pragma unroll
    for (int i = 0; i < 8; ++i) o[i] = (f32x4){0.f,0.f,0.f,0.f};
    float m_r = -1e30f, l_r = 0.f;

    const int nt = qt + 17;
    const size_t pk_base = (((size_t)b*HKV_ + (h>>2))*SP_)*(size_t)D_;
    const size_t kn_base = (((size_t)b*H_   + h     )*SQ_)*(size_t)D_;

    f32x4 kreg[4][2], vreg[2][4];

    auto loadKV = [&](const float* ks, const float* vs) {
        #pragma unroll
        for (int i = 0; i < 4; ++i) {
            int idx = i*256 + tid, row = idx >> 4, c8 = idx & 15;
            kreg[i][0] = *(const f32x4*)(ks + row*D_ + c8*8);
            kreg[i][1] = *(const f32x4*)(ks + row*D_ + c8*8 + 4);
        }
        #pragma unroll
        for (int i = 0; i < 2; ++i) {
            int blk = i*256 + tid, bk = blk & 15, bd = blk >> 4;
            #pragma unroll
            for (int kk = 0; kk < 4; ++kk)
                vreg[i][kk] = *(const f32x4*)(vs + (4*bk+kk)*D_ + bd*4);
        }
    };

    // ---- prologue: tile 0 (always past) -> regs ----
    loadKV(PK + pk_base, PV + pk_base);

    for (int kt = 0; kt < nt; ++kt) {
        const int k0 = kt * KVBLK;
        __syncthreads();   // (A) prev compute done with LDS; staged regs complete here

        // ---- staged regs -> LDS (fp32->bf16, swizzled) ----
        #pragma unroll
        for (int i = 0; i < 4; ++i) {
            int idx = i*256 + tid, row = idx >> 4, c8 = idx & 15;
            bf16x8 f;
            #pragma unroll
            for (int j = 0; j < 4; ++j) {
                f[j]   = f2bf(kreg[i][0][j]);
                f[j+4] = f2bf(kreg[i][1][j]);
            }
            int off = (row*256 + c8*16) ^ ((row & 7) << 4);
            *(bf16x8*)((char*)Klds + off) = f;
        }
        #pragma unroll
        for (int i = 0; i < 2; ++i) {
            int blk = i*256 + tid, bk = blk & 15, bd = blk >> 4;
            #pragma unroll
            for (int j = 0; j < 4; ++j) {
                int d = 4*bd + j;
                bf16x4 t;
                t[0]=f2bf(vreg[i][0][j]); t[1]=f2bf(vreg[i][1][j]);
                t[2]=f2bf(vreg[i][2][j]); t[3]=f2bf(vreg[i][3][j]);
                int off = (d*128 + bk*8) ^ ((d & 7) << 4);
                *(bf16x4*)((char*)Vlds + off) = t;
            }
        }
        __syncthreads();   // (B) LDS(kt) ready

        // ---- prefetch next tile -> regs (in flight during compute, used after next (A)) ----
        if (kt + 1 < nt) {
            const int k1 = k0 + KVBLK;
            const float* ks = (k1 < SP_) ? PK + pk_base + (size_t)k1*D_
                                         : Kin + kn_base + (size_t)(k1 - SP_)*D_;
            const float* vs = (k1 < SP_) ? PV + pk_base + (size_t)k1*D_
                                         : Vin + kn_base + (size_t)(k1 - SP_)*D_;
            loadKV(ks, vs);
        }

        // ---- QK^T swapped: lane holds k = n*16+lg*4+r, q = lr ----
        f32x4 s[4];
        #pragma unroll
        for (int n = 0; n < 4; ++n) s[n] = (f32x4){0.f,0.f,0.f,0.f};
        #pragma unroll
        for (int n = 0; n < 4; ++n) {
            #pragma unroll
            for (int c = 0; c < 4; ++c) {
                int off = ((n*16 + lr)*256 + c*64 + lg*16) ^ ((lr & 7) << 4);
                bf16x8 kf = *(const bf16x8*)((char*)Klds + off);
                s[n] = __builtin_amdgcn_mfma_f32_16x16x32_bf16(kf, qf[c], s[n], 0, 0, 0);
            }
        }

        // ---- causal mask ----
        float p[16];
        const bool needmask = (k0 + KVBLK - 1) > (q0w + SP_);
        if (needmask) {
            const int qv = q0w + lr + SP_;
            #pragma unroll
            for (int n = 0; n < 4; ++n)
                #pragma unroll
                for (int r = 0; r < 4; ++r) {
                    int kg = k0 + n*16 + lg*4 + r;
                    p[n*4+r] = (kg <= qv) ? s[n][r] : -1e30f;
                }
        } else {
            #pragma unroll
            for (int n = 0; n < 4; ++n)
                #pragma unroll
                for (int r = 0; r < 4; ++r) p[n*4+r] = s[n][r];
        }

        // ---- online softmax with defer-max (T13, THR=8 in log2 domain) ----
        float mx = p[0];
        #pragma unroll
        for (int i = 1; i < 16; ++i) mx = fmaxf(mx, p[i]);
        mx = fmaxf(mx, __shfl_xor(mx, 16));
        mx = fmaxf(mx, __shfl_xor(mx, 32));
        if (!__all(mx <= m_r + 8.0f)) {
            float mnew  = fmaxf(m_r, mx);
            float alpha = exp2f(m_r - mnew);
            m_r = mnew;
            l_r *= alpha;
            #pragma unroll
            for (int dt = 0; dt < 8; ++dt) {
                o[dt][0] *= alpha; o[dt][1] *= alpha;
                o[dt][2] *= alpha; o[dt][3] *= alpha;
            }
        }
        float psum = 0.f;
        #pragma unroll
        for (int i = 0; i < 16; ++i) { p[i] = exp2f(p[i] - m_r); psum += p[i]; }
        psum += __shfl_xor(psum, 16);
        psum += __shfl_xor(psum, 32);
        l_r += psum;

        // ---- P -> per-wave LDS (swizzled) ----
        char* Pw = (char*)Plds + w*2048;
        #pragma unroll
        for (int n = 0; n < 4; ++n) {
            bf16x4 t;
            t[0]=f2bf(p[n*4+0]); t[1]=f2bf(p[n*4+1]);
            t[2]=f2bf(p[n*4+2]); t[3]=f2bf(p[n*4+3]);
            int off = (lr*128 + n*32 + lg*8) ^ ((lr & 7) << 4);
            *(bf16x4*)(Pw + off) = t;
        }

        // ---- PV swapped: O^T[d][q] += mfma(V, P) ----
        #pragma unroll
        for (int kk = 0; kk < 2; ++kk) {
            int poff = (lr*128 + kk*64 + lg*16) ^ ((lr & 7) << 4);
            bf16x8 pa = *(const bf16x8*)(Pw + poff);
            #pragma unroll
            for (int dt = 0; dt < 8; ++dt) {
                int voff = ((dt*16 + lr)*128 + kk*64 + lg*16) ^ ((lr & 7) << 4);
                bf16x8 vf = *(const bf16x8*)((char*)Vlds + voff);
                o[dt] = __builtin_amdgcn_mfma_f32_16x16x32_bf16(vf, pa, o[dt], 0, 0, 0);
            }
        }
    }

    // ---- epilogue: lane owns q-row q0w+lr ----
    float inv = 1.0f / l_r;
    float* orow = Out + (((size_t)b*H_ + h)*SQ_ + q0w + lr)*(size_t)D_;
    #pragma unroll
    for (int dt = 0; dt < 8; ++dt) {
        f32x4 st;
        st[0]=o[dt][0]*inv; st[1]=o[dt][1]*inv;
        st[2]=o[dt][2]*inv; st[3]=o[dt][3]*inv;
        *(f32x4*)(orow + dt*16 + lg*4) = st;
    }
}

extern "C" void kernel_launch(void* const* d_in, const int* in_sizes, int n_in,
                              void* d_out, int out_size, void* d_ws, size_t ws_size,
                              hipStream_t stream) {
    const float* Q   = (const float*)d_in[0];
    const float* K   = (const float*)d_in[1];
    const float* V   = (const float*)d_in[2];
    const float* PK  = (const float*)d_in[3];
    const float* PV  = (const float*)d_in[4];
    float* out = (float*)d_out;
    float* opk = out + (size_t)B_*H_*SQ_*D_;
    float* opv = opk + (size_t)B_*HKV_*SK_*D_;

    attn_fused_kernel<<<576, 256, 0, stream>>>(Q, K, V, PK, PV, out, opk, opv);
}